// Round 1
// baseline (30916.074 us; speedup 1.0000x reference)
//
#include <hip/hip_runtime.h>

// ============================================================================
// Two-level LSTM (char k-mer LSTM -> word LSTM), MI355X.
//
// Serial recurrences are executed by persistent multi-workgroup kernels.
// Weight shards live in VGPRs (64 f32/thread). Cross-WG h broadcast uses
// tagged 8-byte slots: (tag=step+1)<<32 | f32bits(h), double-buffered by step
// parity, agent-scope relaxed atomics. Exact-tag polling; 0xAA poison never
// matches a valid tag, so no workspace init is required (graph-replay safe).
// ============================================================================

#define S_LEN 4096
#define TCH   16384        // S_LEN * 4 char steps
#define ALPHA 25
#define ECH   64
#define HR    256
#define DL    128
#define EW    128
#define HW    512
#define GC    16           // char-LSTM workgroups (16 units each)
#define GW    32           // word-LSTM workgroups (16 units each)

static __device__ __forceinline__ float sigmoidf_(float x) {
  return 1.0f / (1.0f + __expf(-x));
}

// ---------------------------------------------------------------------------
// K1a: char gate-input table: table[a][row] = b_r[row] + E_char[a,:]·W_ih_r[row,:]
// Only 25 distinct chars -> the entire x@W_ih_r^T is a 25x1024 lookup.
// ---------------------------------------------------------------------------
__global__ void k_table(const float* __restrict__ Ec, const float* __restrict__ Wih,
                        const float* __restrict__ br, float* __restrict__ table) {
  __shared__ __align__(16) float e[ECH];
  int a = blockIdx.x, tid = threadIdx.x;
  if (tid < ECH) e[tid] = Ec[a * ECH + tid];
  __syncthreads();
  for (int row = tid; row < 4 * HR; row += 256) {
    const float4* w = (const float4*)(Wih + row * ECH);
    const float4* e4 = (const float4*)e;
    float acc = 0.f;
#pragma unroll
    for (int j = 0; j < ECH / 4; ++j) {
      float4 wv = w[j], ev = e4[j];
      acc += wv.x * ev.x + wv.y * ev.y + wv.z * ev.z + wv.w * ev.w;
    }
    table[a * (4 * HR) + row] = acc + br[row];
  }
}

// ---------------------------------------------------------------------------
// K1b: permute W_ih_w into k-major layout WT[k][p] where p enumerates
// (wg, gate, unit) so the word kernel's per-step x-slice reads are contiguous.
// ---------------------------------------------------------------------------
__global__ void k_permw(const float* __restrict__ Wihw, const float* __restrict__ bw,
                        float* __restrict__ WT, float* __restrict__ bperm) {
  int e = blockIdx.x * 256 + threadIdx.x;      // 2048 blocks * 256 = 2048*256
  int p = e >> 8, k = e & 255;
  int r = p & 63, wgp = p >> 6;
  int R = (r >> 4) * HW + wgp * 16 + (r & 15); // global row in [0,2048)
  WT[k * (4 * HW) + p] = Wihw[R * (EW + DL) + k];
  if (k == 0) bperm[p] = bw[R];
}

// ---------------------------------------------------------------------------
// K2: persistent char LSTM. 16 WGs x 256 threads. WG owns 16 hidden units
// (64 gate rows). wave w covers k in [64w,64w+64); lane l owns local row l
// (row = gate*16+unit, gate = l>>4). Weights in VGPRs (16 x float4).
// ---------------------------------------------------------------------------
__global__ __launch_bounds__(256) void k_char_lstm(
    const int* __restrict__ char_ids, const float* __restrict__ Whh,
    const float* __restrict__ table, unsigned long long* __restrict__ slots,
    float* __restrict__ h_word)
{
  const int wg = blockIdx.x;
  const int tid = threadIdx.x;
  const int wave = tid >> 6, lane = tid & 63;
  const int R = (lane >> 4) * HR + wg * 16 + (lane & 15);
  float4 wreg[16];
  {
    const float4* wp = (const float4*)(Whh + R * HR + wave * 64);
#pragma unroll
    for (int j = 0; j < 16; ++j) wreg[j] = wp[j];
  }
  __shared__ __align__(16) float tab[ALPHA * 64];
  __shared__ __align__(16) float hst[4][64];
  __shared__ float part[4][64];
  __shared__ float zbuf[64];
  __shared__ float cst[16];
  for (int i = tid; i < ALPHA * 64; i += 256) {
    int ch = i >> 6, r = i & 63;
    int Rr = (r >> 4) * HR + wg * 16 + (r & 15);
    tab[i] = table[ch * (4 * HR) + Rr];
  }
  hst[wave][lane] = 0.f;
  if (tid < 16) cst[tid] = 0.f;
  __syncthreads();

#pragma unroll 1
  for (int t = 0; t < TCH; ++t) {
    int ch = char_ids[t];                    // uniform; overlaps the poll below
    if (t > 0) {
      // poll h_{t-1}: slot parity (t-1)&1, tag t. Thread tid polls h[tid],
      // which is exactly wave `tid>>6`'s k-slice element.
      unsigned long long v;
      unsigned long long* sl = slots + (((t - 1) & 1) ? HR : 0) + tid;
      do {
        v = __hip_atomic_load(sl, __ATOMIC_RELAXED, __HIP_MEMORY_SCOPE_AGENT);
      } while ((unsigned)(v >> 32) != (unsigned)t);
      hst[wave][lane] = __uint_as_float((unsigned)v);
      // same-wave LDS write->read is ordered; no barrier needed.
    }
    const float4* hp = (const float4*)hst[wave];
    float acc = 0.f;
#pragma unroll
    for (int j = 0; j < 16; ++j) {
      float4 h4 = hp[j];
      acc += wreg[j].x * h4.x + wreg[j].y * h4.y + wreg[j].z * h4.z + wreg[j].w * h4.w;
    }
    part[wave][lane] = acc;
    __syncthreads();
    if (wave == 0) {
      float z = part[0][lane] + part[1][lane] + part[2][lane] + part[3][lane]
              + tab[ch * 64 + lane];
      zbuf[lane] = z;                        // within-wave redistribute
      if (lane < 16) {
        float zi = zbuf[lane], zf = zbuf[16 + lane];
        float zg = zbuf[32 + lane], zo = zbuf[48 + lane];
        float c = cst[lane];
        float ig = sigmoidf_(zi), fg = sigmoidf_(zf), og = sigmoidf_(zo);
        float gg = tanhf(zg);
        c = fg * c + ig * gg;
        cst[lane] = c;
        float h = og * tanhf(c);
        unsigned long long pv =
            (((unsigned long long)(unsigned)(t + 1)) << 32) |
            (unsigned long long)__float_as_uint(h);
        __hip_atomic_store(slots + ((t & 1) ? HR : 0) + wg * 16 + lane, pv,
                           __ATOMIC_RELAXED, __HIP_MEMORY_SCOPE_AGENT);
        if ((t & 3) == 3) h_word[(t >> 2) * HR + wg * 16 + lane] = h;
      }
    }
    __syncthreads();                         // protect part[] before next iter
  }
}

// ---------------------------------------------------------------------------
// K3a: latent = tanh(h_word @ W_lat^T + b_lat). One block per word.
// ---------------------------------------------------------------------------
__global__ __launch_bounds__(128) void k_latent(
    const float* __restrict__ hw, const float* __restrict__ Wlat,
    const float* __restrict__ blat, float* __restrict__ lat)
{
  int t = blockIdx.x, d = threadIdx.x;
  __shared__ __align__(16) float hh[HR];
  ((float2*)hh)[d] = ((const float2*)(hw + t * HR))[d];
  __syncthreads();
  const float4* w = (const float4*)(Wlat + d * HR);
  const float4* h4 = (const float4*)hh;
  float acc = 0.f;
#pragma unroll 8
  for (int j = 0; j < HR / 4; ++j) {
    float4 wv = w[j], hv = h4[j];
    acc += wv.x * hv.x + wv.y * hv.y + wv.z * hv.z + wv.w * hv.w;
  }
  lat[t * DL + d] = tanhf(acc + blat[d]);
}

// ---------------------------------------------------------------------------
// K3b: Xw[t][p] = bperm[p] + concat(E_word[wid[t]], latent[t]) · W row(p)
// Tiles: 32 words x 256 p per block; x-tile staged in LDS; WT reads coalesced.
// ---------------------------------------------------------------------------
__global__ __launch_bounds__(256) void k_xw(
    const float* __restrict__ Ew, const int* __restrict__ wid,
    const float* __restrict__ lat, const float* __restrict__ WT,
    const float* __restrict__ bperm, float* __restrict__ Xw)
{
  int tblk = blockIdx.x, pblk = blockIdx.y;
  int tid = threadIdx.x;
  int p = pblk * 256 + tid;
  __shared__ __align__(16) float xt[32][256];
  int t0 = tblk * 32;
  for (int i = tid; i < 32 * 256; i += 256) {
    int tl = i >> 8, e = i & 255;
    int t = t0 + tl;
    float v;
    if (e < 128) v = Ew[wid[t] * EW + e];
    else         v = lat[t * DL + (e - 128)];
    xt[tl][e] = v;
  }
  __syncthreads();
  float acc[32];
#pragma unroll
  for (int i = 0; i < 32; ++i) acc[i] = 0.f;
  for (int k = 0; k < 256; k += 4) {
    float w0 = WT[(k + 0) * (4 * HW) + p];
    float w1 = WT[(k + 1) * (4 * HW) + p];
    float w2 = WT[(k + 2) * (4 * HW) + p];
    float w3 = WT[(k + 3) * (4 * HW) + p];
#pragma unroll
    for (int tl = 0; tl < 32; ++tl) {
      float4 x4 = *(const float4*)&xt[tl][k];
      acc[tl] += w0 * x4.x + w1 * x4.y + w2 * x4.z + w3 * x4.w;
    }
  }
  float b = bperm[p];
#pragma unroll
  for (int tl = 0; tl < 32; ++tl)
    Xw[(t0 + tl) * (4 * HW) + p] = acc[tl] + b;
}

// ---------------------------------------------------------------------------
// K4: persistent word LSTM. 32 WGs x 512 threads (8 waves). Same structure as
// K2; per-step x-slice prefetched one step ahead from the permuted Xw.
// ---------------------------------------------------------------------------
__global__ __launch_bounds__(512) void k_word_lstm(
    const float* __restrict__ Whh, const float* __restrict__ Xw,
    unsigned long long* __restrict__ slots, float* __restrict__ out)
{
  const int wg = blockIdx.x;
  const int tid = threadIdx.x;
  const int wave = tid >> 6, lane = tid & 63;
  const int R = (lane >> 4) * HW + wg * 16 + (lane & 15);
  float4 wreg[16];
  {
    const float4* wp = (const float4*)(Whh + R * HW + wave * 64);
#pragma unroll
    for (int j = 0; j < 16; ++j) wreg[j] = wp[j];
  }
  __shared__ __align__(16) float hst[8][64];
  __shared__ float part[8][64];
  __shared__ float zbuf[64];
  __shared__ float cst[16];
  hst[wave][lane] = 0.f;
  if (tid < 16) cst[tid] = 0.f;
  __syncthreads();
  float xv = 0.f;
  if (wave == 0) xv = Xw[wg * 64 + lane];    // t=0 slice

#pragma unroll 1
  for (int t = 0; t < S_LEN; ++t) {
    float xn = 0.f;
    if (wave == 0) {                         // prefetch next x-slice
      int tt = (t + 1 < S_LEN) ? (t + 1) : t;
      xn = Xw[tt * (4 * HW) + wg * 64 + lane];
    }
    if (t > 0) {
      unsigned long long v;
      unsigned long long* sl = slots + (((t - 1) & 1) ? HW : 0) + tid;
      do {
        v = __hip_atomic_load(sl, __ATOMIC_RELAXED, __HIP_MEMORY_SCOPE_AGENT);
      } while ((unsigned)(v >> 32) != (unsigned)t);
      hst[wave][lane] = __uint_as_float((unsigned)v);
    }
    const float4* hp = (const float4*)hst[wave];
    float acc = 0.f;
#pragma unroll
    for (int j = 0; j < 16; ++j) {
      float4 h4 = hp[j];
      acc += wreg[j].x * h4.x + wreg[j].y * h4.y + wreg[j].z * h4.z + wreg[j].w * h4.w;
    }
    part[wave][lane] = acc;
    __syncthreads();
    if (wave == 0) {
      float z = xv;
#pragma unroll
      for (int w = 0; w < 8; ++w) z += part[w][lane];
      zbuf[lane] = z;
      if (lane < 16) {
        float zi = zbuf[lane], zf = zbuf[16 + lane];
        float zg = zbuf[32 + lane], zo = zbuf[48 + lane];
        float c = cst[lane];
        float ig = sigmoidf_(zi), fg = sigmoidf_(zf), og = sigmoidf_(zo);
        float gg = tanhf(zg);
        c = fg * c + ig * gg;
        cst[lane] = c;
        float h = og * tanhf(c);
        unsigned long long pv =
            (((unsigned long long)(unsigned)(t + 1)) << 32) |
            (unsigned long long)__float_as_uint(h);
        __hip_atomic_store(slots + ((t & 1) ? HW : 0) + wg * 16 + lane, pv,
                           __ATOMIC_RELAXED, __HIP_MEMORY_SCOPE_AGENT);
        out[t * HW + wg * 16 + lane] = h;
      }
    }
    __syncthreads();
    xv = xn;
  }
}

// ---------------------------------------------------------------------------
extern "C" void kernel_launch(void* const* d_in, const int* in_sizes, int n_in,
                              void* d_out, int out_size, void* d_ws, size_t ws_size,
                              hipStream_t stream) {
  const float* E_char = (const float*)d_in[0];
  const float* W_ih_r = (const float*)d_in[1];
  const float* W_hh_r = (const float*)d_in[2];
  const float* b_r    = (const float*)d_in[3];
  const float* W_lat  = (const float*)d_in[4];
  const float* b_lat  = (const float*)d_in[5];
  const float* E_word = (const float*)d_in[6];
  const float* W_ih_w = (const float*)d_in[7];
  const float* W_hh_w = (const float*)d_in[8];
  const float* b_w    = (const float*)d_in[9];
  const int* word_ids = (const int*)d_in[10];
  const int* char_ids = (const int*)d_in[11];

  char* ws = (char*)d_ws;
  float*              tableR = (float*)(ws + 0x000000);            // 100 KB
  unsigned long long* slotsC = (unsigned long long*)(ws + 0x20000); // 4 KB
  unsigned long long* slotsW = (unsigned long long*)(ws + 0x22000); // 8 KB
  float*              h_word = (float*)(ws + 0x030000);            // 4 MB
  float*              latent = (float*)(ws + 0x430000);            // 2 MB
  float*              WT     = (float*)(ws + 0x630000);            // 2 MB
  float*              bperm  = (float*)(ws + 0x830000);            // 8 KB
  float*              Xw     = (float*)(ws + 0x840000);            // 32 MB
  float* out = (float*)d_out;

  hipLaunchKernelGGL(k_table,     dim3(ALPHA),   dim3(256), 0, stream,
                     E_char, W_ih_r, b_r, tableR);
  hipLaunchKernelGGL(k_permw,     dim3(2048),    dim3(256), 0, stream,
                     W_ih_w, b_w, WT, bperm);
  hipLaunchKernelGGL(k_char_lstm, dim3(GC),      dim3(256), 0, stream,
                     char_ids, W_hh_r, tableR, slotsC, h_word);
  hipLaunchKernelGGL(k_latent,    dim3(S_LEN),   dim3(128), 0, stream,
                     h_word, W_lat, b_lat, latent);
  hipLaunchKernelGGL(k_xw,        dim3(128, 8),  dim3(256), 0, stream,
                     E_word, word_ids, latent, WT, bperm, Xw);
  hipLaunchKernelGGL(k_word_lstm, dim3(GW),      dim3(512), 0, stream,
                     W_hh_w, Xw, slotsW, out);
}